// Round 15
// baseline (730.195 us; speedup 1.0000x reference)
//
#include <hip/hip_runtime.h>
#include <hip/hip_bf16.h>
#include <cstdint>

#define HDIM 256
#define H2   128

using f32x4  = __attribute__((ext_vector_type(4))) float;
using bf16x8 = __attribute__((ext_vector_type(8))) short;    // 8 bf16 in 4 VGPRs
using u16x8  = __attribute__((ext_vector_type(8))) unsigned short;

__device__ inline unsigned short f2bf(float f) {             // round-to-nearest-even
    unsigned x = __builtin_bit_cast(unsigned, f);
    return (unsigned short)((x + 0x7fffu + ((x >> 16) & 1u)) >> 16);
}
__device__ inline float bf2f(unsigned short u) {
    unsigned x = ((unsigned)u) << 16;
    return __builtin_bit_cast(float, x);
}

// ---------------------------------------------------------------------------
// in-degree with XCD-affinity phasing (same mechanism as k_fill8, R14-proven):
// block's xcd = blockIdx&7; counts only cols in its partition -> deg lines
// stay in ONE L2, no cross-XCD atomic line-bounce. ecol re-read 8x (cheap, L3).
__global__ __launch_bounds__(256) void k_deg8(const int* __restrict__ col,
                                              int* __restrict__ deg0, int e) {
    int xcd   = blockIdx.x & 7;
    int chunk = blockIdx.x >> 3;
    int base  = chunk * 2048;
    int end   = base + 2048; if (end > e) end = e;
    for (int i = base + threadIdx.x; i < end; i += 256) {
        int c = col[i];
        if (((c >> 3) & 7) == xcd) atomicAdd(&deg0[c], 1);
    }
}

__global__ void k_scan1(const int* __restrict__ deg0, int* __restrict__ ptr,
                        int* __restrict__ bsum, int n) {
    __shared__ int sd[256];
    int i = blockIdx.x * 256 + threadIdx.x;
    int v = (i < n) ? deg0[i] : 0;
    sd[threadIdx.x] = v;
    __syncthreads();
    for (int off = 1; off < 256; off <<= 1) {
        int t = (threadIdx.x >= off) ? sd[threadIdx.x - off] : 0;
        __syncthreads();
        sd[threadIdx.x] += t;
        __syncthreads();
    }
    if (i < n) ptr[i] = sd[threadIdx.x] - v;
    if (threadIdx.x == 255) bsum[blockIdx.x] = sd[255];
}

__global__ void k_scan2(int* __restrict__ bsum, int nb) {
    __shared__ int sd[512];
    int t = threadIdx.x;
    int v = (t < nb) ? bsum[t] : 0;
    sd[t] = v;
    __syncthreads();
    for (int off = 1; off < 512; off <<= 1) {
        int x = (t >= off) ? sd[t - off] : 0;
        __syncthreads();
        sd[t] += x;
        __syncthreads();
    }
    if (t < nb) bsum[t] = sd[t] - v;
}

// scan finalize + dis = (deg0+1)^-0.5 (self-loop included in norm)
__global__ void k_scan3(int* __restrict__ ptr, const int* __restrict__ bsum,
                        const int* __restrict__ deg0, float* __restrict__ dis, int n) {
    int i = blockIdx.x * 256 + threadIdx.x;
    if (i < n) {
        ptr[i] += bsum[blockIdx.x];
        dis[i] = rsqrtf((float)deg0[i] + 1.0f);
    }
}

// CSR fill with XCD-affinity phasing (R14: dropped 124us -> invisible).
__global__ __launch_bounds__(256) void k_fill8(const int* __restrict__ row,
                                               const int* __restrict__ col,
                                               const int* __restrict__ ptr,
                                               int* __restrict__ cursor,
                                               int* __restrict__ csr, int e) {
    int xcd   = blockIdx.x & 7;
    int chunk = blockIdx.x >> 3;
    int base  = chunk * 2048;
    int end   = base + 2048; if (end > e) end = e;
    for (int i = base + threadIdx.x; i < end; i += 256) {
        int c = col[i];
        if (((c >> 3) & 7) == xcd) {
            int s = atomicAdd(&cursor[c], 1);
            csr[ptr[c] + s] = row[i];
        }
    }
}

// fused: Wt transpose-convert (blocks 0..767) + emb fp32->bf16 (768..)
__global__ void k_prep(const float* __restrict__ W1, const float* __restrict__ W2,
                       const float* __restrict__ W3, short* __restrict__ Wt1,
                       short* __restrict__ Wt2, short* __restrict__ Wt3,
                       const float* __restrict__ emb, short* __restrict__ embb,
                       int embtot) {
    int b = blockIdx.x;
    if (b < 768) {
        int layer = b >> 8;
        const float* W = (layer == 0) ? W1 : (layer == 1) ? W2 : W3;
        short* Wt      = (layer == 0) ? Wt1 : (layer == 1) ? Wt2 : Wt3;
        int i = (b & 255) * 256 + threadIdx.x;
        int nn = i >> 8, k = i & 255;
        Wt[nn * HDIM + k] = (short)f2bf(W[k * HDIM + nn]);
    } else {
        int i = (b - 768) * 256 + threadIdx.x;
        if (i < embtot) embb[i] = (short)f2bf(emb[i]);
    }
}

// AtomEncoder from bf16 table (L2-resident): wave per node, lane = 4 cols
__global__ __launch_bounds__(256) void k_atom(const int* __restrict__ x,
                                              const short* __restrict__ embb,
                                              short* __restrict__ h,
                                              int n, int F, int V) {
    int node = blockIdx.x * 4 + (threadIdx.x >> 6);
    int lane = threadIdx.x & 63;
    if (node >= n) return;
    int xv = x[node * F + (lane < F ? lane : 0)];
    float acc[4] = {};
    for (int f = 0; f < F; ++f) {
        int idx = __shfl(xv, f, 64);
        ushort4 v = *(const ushort4*)((const unsigned short*)embb +
                                      ((size_t)(f * V + idx)) * HDIM + lane * 4);
        acc[0] += bf2f(v.x); acc[1] += bf2f(v.y);
        acc[2] += bf2f(v.z); acc[3] += bf2f(v.w);
    }
    ushort4 o = { f2bf(acc[0]), f2bf(acc[1]), f2bf(acc[2]), f2bf(acc[3]) };
    *(ushort4*)(h + (size_t)node * HDIM + lane * 4) = o;
}

// bf16 MFMA GEMM with 2-PHASE K-PIPELINE (T3-lite).
// LDS = [2 phases][64 rows][256B half-K]. All 8 global_load_lds issued up
// front; s_waitcnt vmcnt(4) + raw barrier -> compute K[0,128) while phase-1
// loads are in flight; vmcnt(0) + barrier -> compute K[128,256).
// Per-wave vmcnt guarantees own loads done; barrier joins -> all done.
// Swizzle per half-row: byte ^= ((r&7)<<4), inverse applied on global source.
__global__ __launch_bounds__(256, 4) void k_gemm(const short* __restrict__ A,
                                                 const short* __restrict__ Wt,
                                                 short* __restrict__ Co, int n) {
    __shared__ unsigned char As[2 * 64 * 256];   // 32 KB
    int row0 = blockIdx.x * 64;
    int t = threadIdx.x;
    int wid  = t >> 6;
    int lane = t & 63;
#pragma unroll
    for (int p = 0; p < 2; ++p)
#pragma unroll
        for (int jj = 0; jj < 4; ++jj) {
            int ci = (wid * 4 + jj) * 64 + lane;     // 0..1023
            int r  = ci >> 4;                        // row 0..63
            int kb = (ci & 15) * 16;                 // byte within 256B half
            int gr = row0 + r; if (gr >= n) gr = n - 1;
            const unsigned int* g = (const unsigned int*)
                ((const char*)A + (size_t)gr * 512 + p * 256 + (kb ^ ((r & 7) << 4)));
            unsigned int* l = (unsigned int*)(As + p * 16384 + (size_t)(wid * 4 + jj) * 1024);
            __builtin_amdgcn_global_load_lds(g, l, 16, 0, 0);
        }

    int lm = lane & 15;
    int kg = lane >> 4;
    int colw = wid * 64;                          // each wave owns 64 cols
    f32x4 acc[4][4] = {};

    asm volatile("s_waitcnt vmcnt(4)" ::: "memory");   // phase-0 (own) done
    __builtin_amdgcn_s_barrier();                      // join: all phase-0 done
    __builtin_amdgcn_sched_barrier(0);

#pragma unroll
    for (int kk = 0; kk < 8; ++kk) {              // k-chunk of 32 elems (64 B)
        if (kk == 4) {
            asm volatile("s_waitcnt vmcnt(0)" ::: "memory");  // phase-1 done
            __builtin_amdgcn_s_barrier();
            __builtin_amdgcn_sched_barrier(0);
        }
        int p = kk >> 2;
        bf16x8 a[4], b[4];
#pragma unroll
        for (int i = 0; i < 4; ++i) {
            int R = i * 16 + lm;
            int boff = ((kk & 3) * 64 + kg * 16) ^ ((R & 7) << 4);
            a[i] = *(const bf16x8*)(As + p * 16384 + R * 256 + boff);
        }
#pragma unroll
        for (int j = 0; j < 4; ++j) {
            int cidx = colw + j * 16 + lm;
            b[j] = *(const bf16x8*)(Wt + (size_t)cidx * HDIM + kk * 32 + kg * 8);
        }
#pragma unroll
        for (int i = 0; i < 4; ++i)
#pragma unroll
            for (int j = 0; j < 4; ++j)
                acc[i][j] = __builtin_amdgcn_mfma_f32_16x16x32_bf16(a[i], b[j], acc[i][j], 0, 0, 0);
    }
#pragma unroll
    for (int i = 0; i < 4; ++i)
#pragma unroll
        for (int j = 0; j < 4; ++j) {
            int c = colw + j * 16 + lm;
#pragma unroll
            for (int r4 = 0; r4 < 4; ++r4) {
                int r = row0 + i * 16 + kg * 4 + r4;
                if (r < n) Co[(size_t)r * HDIM + c] = (short)f2bf(acc[i][j][r4]);
            }
        }
}

// gather-aggregate: wave per node, supersteps of 8 edges with 4 independent
// row loads in flight per lane. 32 lanes x ushort8 = one 512B message row;
// halves split even/odd edges; final xor-32 reduce merges them.
// Structurally pinned at L2-miss/L3 path ~3.9 TB/s (R6-R14: ~124us, FETCH 417MB).
__global__ __launch_bounds__(256) void k_agg(const short* __restrict__ mS,
                                             const int* __restrict__ csr_src,
                                             const int* __restrict__ ptr,
                                             const int* __restrict__ deg0,
                                             const float* __restrict__ dis,
                                             const float* __restrict__ bias,
                                             short* __restrict__ xout, int n) {
    int node = blockIdx.x * 4 + (threadIdx.x >> 6);
    if (node >= n) return;
    int lane = threadIdx.x & 63;
    int half = lane >> 5;
    int cl = lane & 31;                       // col group: 8 cols
    const unsigned short* m = (const unsigned short*)mS;
    float dv = dis[node];
    float acc[8] = {};
    if (half == 0) {                          // self-loop term
        u16x8 r = *(const u16x8*)(m + (size_t)node * HDIM + cl * 8);
        float sw = dv * dv;
#pragma unroll
        for (int j = 0; j < 8; ++j) acc[j] = sw * bf2f(r[j]);
    }
    int start = ptr[node];
    int cnt = deg0[node];
    for (int base = 0; base < cnt; base += 64) {
        int mm = cnt - base; if (mm > 64) mm = 64;
        int uu = 0; float du = 0.f;
        if (lane < mm) {
            uu = __builtin_nontemporal_load(&csr_src[start + base + lane]);
            du = dis[uu];
        }
        int nst = (mm + 7) >> 3;              // supersteps of 8 edges (4/half)
        for (int s = 0; s < nst; ++s) {
            u16x8 r[4]; float w[4];
#pragma unroll
            for (int q = 0; q < 4; ++q) {     // issue 4 independent loads
                int i = 8 * s + 2 * q + half;
                int u   = __shfl(uu, i & 63, 64);
                float ww = dv * __shfl(du, i & 63, 64);
                bool v = i < mm;
                w[q] = v ? ww : 0.f;
                r[q] = *(const u16x8*)(m + (size_t)(v ? u : 0) * HDIM + cl * 8);
            }
#pragma unroll
            for (int q = 0; q < 4; ++q)
#pragma unroll
                for (int j = 0; j < 8; ++j) acc[j] += w[q] * bf2f(r[q][j]);
        }
    }
#pragma unroll
    for (int j = 0; j < 8; ++j) acc[j] += __shfl_xor(acc[j], 32, 64);
    if (half == 0) {
        const float4 b0 = *(const float4*)(bias + cl * 8);
        const float4 b1 = *(const float4*)(bias + cl * 8 + 4);
        float bb[8] = {b0.x, b0.y, b0.z, b0.w, b1.x, b1.y, b1.z, b1.w};
        u16x8 o;
#pragma unroll
        for (int j = 0; j < 8; ++j)
            o[j] = f2bf(fmaxf(acc[j] + bb[j], 0.f));
        *(u16x8*)((unsigned short*)xout + (size_t)node * HDIM + cl * 8) = o;
    }
}

// pooling, partial-sum form (atomic-free): grid (B, 4). Block (g, seg) sums
// its quarter of graph g's rows over x1+x2+x3 -> partial[(seg*B+g)*HDIM+t].
__global__ __launch_bounds__(256) void k_pool(const short* __restrict__ x1,
                                              const short* __restrict__ x2,
                                              const short* __restrict__ x3,
                                              const int* __restrict__ batch,
                                              float* __restrict__ partial,
                                              int n, int B) {
    __shared__ float spool[8][HDIM];
    int g = blockIdx.x, seg = blockIdx.y, t = threadIdx.x;
    int cg = t & 31, rl = t >> 5;
    auto lb = [&](int key) {
        int lo = 0, hi = n;
        while (lo < hi) { int mid = (lo + hi) >> 1; if (batch[mid] < key) lo = mid + 1; else hi = mid; }
        return lo;
    };
    int lo = lb(g), hi = lb(g + 1);
    int len = hi - lo;
    int per = (len + 3) >> 2;
    int s0 = lo + seg * per;
    int s1 = s0 + per; if (s1 > hi) s1 = hi;
    float acc[8] = {};
    for (int r = s0 + rl; r < s1; r += 8) {
        size_t base = (size_t)r * HDIM + cg * 8;
        u16x8 a = *(const u16x8*)((const unsigned short*)x1 + base);
        u16x8 b = *(const u16x8*)((const unsigned short*)x2 + base);
        u16x8 c = *(const u16x8*)((const unsigned short*)x3 + base);
#pragma unroll
        for (int j = 0; j < 8; ++j)
            acc[j] += bf2f(a[j]) + bf2f(b[j]) + bf2f(c[j]);
    }
#pragma unroll
    for (int j = 0; j < 8; ++j) spool[rl][cg * 8 + j] = acc[j];
    __syncthreads();
    float s = 0.f;
#pragma unroll
    for (int r2 = 0; r2 < 8; ++r2) s += spool[r2][t];
    partial[(size_t)(seg * B + g) * HDIM + t] = s;
}

// classifier: sum 4 partials, divide by count (binary search), 2-layer MLP.
__global__ __launch_bounds__(256) void k_cls(const float* __restrict__ partial,
                                             const int* __restrict__ batch,
                                             const float* __restrict__ cw1,
                                             const float* __restrict__ cb1,
                                             const float* __restrict__ cw2,
                                             const float* __restrict__ cb2,
                                             float* __restrict__ out,
                                             int n, int B, int C) {
    __shared__ float sp[HDIM];
    __shared__ float sh[H2];
    int g = blockIdx.x, t = threadIdx.x;
    auto lb = [&](int key) {
        int lo = 0, hi = n;
        while (lo < hi) { int mid = (lo + hi) >> 1; if (batch[mid] < key) lo = mid + 1; else hi = mid; }
        return lo;
    };
    int lo = lb(g), hi = lb(g + 1);
    int cnt = hi - lo; if (cnt < 1) cnt = 1;
    float s = 0.f;
#pragma unroll
    for (int seg = 0; seg < 4; ++seg)
        s += partial[(size_t)(seg * B + g) * HDIM + t];
    sp[t] = s / (float)cnt;
    __syncthreads();
    if (t < H2) {
        float a = cb1[t];
        for (int h = 0; h < HDIM; ++h) a += sp[h] * cw1[h * H2 + t];
        sh[t] = fmaxf(a, 0.f);
    }
    __syncthreads();
    if (t < C) {
        float o = cb2[t];
        for (int j = 0; j < H2; ++j) o += sh[j] * cw2[j * C + t];
        out[g * C + t] = o;
    }
    if (g == 0 && t == 0) out[B * C] = 0.f;
}

// ---------------------------------------------------------------------------
extern "C" void kernel_launch(void* const* d_in, const int* in_sizes, int n_in,
                              void* d_out, int out_size, void* d_ws, size_t ws_size,
                              hipStream_t stream) {
    const int* x      = (const int*)d_in[0];
    const int* erow   = (const int*)d_in[1];
    const int* batch  = (const int*)d_in[2];
    const float* emb  = (const float*)d_in[3];
    const float* W1   = (const float*)d_in[4];
    const float* b1   = (const float*)d_in[5];
    const float* W2   = (const float*)d_in[6];
    const float* b2   = (const float*)d_in[7];
    const float* W3   = (const float*)d_in[8];
    const float* b3   = (const float*)d_in[9];
    const float* cw1  = (const float*)d_in[10];
    const float* cb1  = (const float*)d_in[11];
    const float* cw2  = (const float*)d_in[12];
    const float* cb2  = (const float*)d_in[13];
    float* out = (float*)d_out;

    const int N = in_sizes[2];
    const int E = in_sizes[1] / 2;
    const int F = in_sizes[0] / N;
    const int V = in_sizes[3] / (F * HDIM);
    const int C = in_sizes[13];
    const int B = (out_size - 1) / C;
    const int* ecol = erow + E;
    const int EMBTOT = F * V * HDIM;

    char* w = (char*)d_ws;
    auto carve = [&](size_t bytes) {
        void* p = (void*)w;
        w += (bytes + 255) & ~(size_t)255;
        return p;
    };
    short* P0     = (short*)carve((size_t)N * HDIM * 2);   // h0, later x3
    short* P1     = (short*)carve((size_t)N * HDIM * 2);   // x1
    short* P2     = (short*)carve((size_t)N * HDIM * 2);   // x2
    short* mS     = (short*)carve((size_t)N * HDIM * 2);   // GEMM output (messages)
    short* embb   = (short*)carve((size_t)EMBTOT * 2);
    short* Wt1    = (short*)carve((size_t)HDIM * HDIM * 2);
    short* Wt2    = (short*)carve((size_t)HDIM * HDIM * 2);
    short* Wt3    = (short*)carve((size_t)HDIM * HDIM * 2);
    float* partial= (float*)carve((size_t)4 * B * HDIM * 4);
    float* dis    = (float*)carve((size_t)N * 4);
    int* deg0     = (int*)carve((size_t)N * 4);
    int* ptr      = (int*)carve((size_t)N * 4);
    int* cursor   = (int*)carve((size_t)N * 4);
    int* bsum     = (int*)carve(1024 * 4);
    int* csr      = (int*)carve((size_t)E * 4);

    int nblk = (N + 255) / 256;
    int nch = (E + 2047) / 2048;

    hipMemsetAsync(deg0, 0, (size_t)N * 4, stream);
    hipMemsetAsync(cursor, 0, (size_t)N * 4, stream);
    k_deg8<<<nch * 8, 256, 0, stream>>>(ecol, deg0, E);
    k_scan1<<<nblk, 256, 0, stream>>>(deg0, ptr, bsum, N);
    k_scan2<<<1, 512, 0, stream>>>(bsum, nblk);
    k_scan3<<<nblk, 256, 0, stream>>>(ptr, bsum, deg0, dis, N);
    k_fill8<<<nch * 8, 256, 0, stream>>>(erow, ecol, ptr, cursor, csr, E);
    int prep_blocks = 768 + (EMBTOT + 255) / 256;
    k_prep<<<prep_blocks, 256, 0, stream>>>(W1, W2, W3, Wt1, Wt2, Wt3, emb, embb, EMBTOT);
    k_atom<<<(N + 3) / 4, 256, 0, stream>>>(x, embb, P0, N, F, V);

    int ggrid = (N + 63) / 64;
    int agrid = (N + 3) / 4;

    k_gemm<<<ggrid, 256, 0, stream>>>(P0, Wt1, mS, N);
    k_agg<<<agrid, 256, 0, stream>>>(mS, csr, ptr, deg0, dis, b1, P1, N);
    k_gemm<<<ggrid, 256, 0, stream>>>(P1, Wt2, mS, N);
    k_agg<<<agrid, 256, 0, stream>>>(mS, csr, ptr, deg0, dis, b2, P2, N);
    k_gemm<<<ggrid, 256, 0, stream>>>(P2, Wt3, mS, N);
    k_agg<<<agrid, 256, 0, stream>>>(mS, csr, ptr, deg0, dis, b3, P0, N);

    dim3 pgrid(B, 4);
    k_pool<<<pgrid, 256, 0, stream>>>(P1, P2, P0, batch, partial, N, B);
    k_cls<<<B, 256, 0, stream>>>(partial, batch, cw1, cb1, cw2, cb2, out, N, B, C);
}